// Round 1
// 67.676 us; speedup vs baseline: 1.0057x; 1.0057x over previous
//
#include <hip/hip_runtime.h>
#include <math.h>

// Problem constants (from reference)
#define FH 64    // feature map H (axis indexed by x)
#define FW 64    // feature map W (axis indexed by y)
#define FC 256   // channels
#define PP 7     // pool output dim
#define NROI 256
#define CH 4     // pipeline chunk: 4 loads in flight per stage, 2 stages

typedef float f32x4 __attribute__((ext_vector_type(4)));

// Exact replication of reference _bin_bounds integer math.
__device__ __forceinline__ void bin_bounds(int lo, int span, int idx, int size,
                                           int& start, int& len) {
    int s0 = lo + (idx * span) / PP;                   // nonneg -> floor div
    int e0 = lo + ((idx + 1) * span + (PP - 1)) / PP;  // ceil div (nonneg)
    int l = e0 - s0;
    len = l > 1 ? l : 1;
    int s = s0 < 0 ? 0 : s0;
    start = s > (size - 1) ? (size - 1) : s;
}

// One 64-lane wave per output cell (r,i,j). The xlen*ylen window is walked
// linearly with wave-uniform (sx,sy) counters. v2 changes vs v1 (67.6us):
//  - readfirstlane(cell): all per-cell control state (bin bounds, walk
//    counters, trip counts) is provably wave-uniform -> SALU + s_load rois,
//    scalar branches instead of exec-mask divergence.
//  - CH=8 -> CH=4 with a 2-stage software pipeline: loads of chunk k+1 are
//    issued before the fmax of chunk k, so the compiler waits vmcnt(4)
//    instead of vmcnt(0) (latency overlapped with next-chunk issue + fmax).
//    CH=4 also cuts tail-duplicate loads from ~45% to ~15% of VMEM traffic.
//  - nontemporal output store: 12.8 MB streaming writes no longer evict the
//    4 MB featMap from the 4 MiB per-XCD L2.
// Tail slots re-load the final valid pixel (duplicate under max = no-op).
// lane = 4-channel group, 1KB coalesced per load instruction.
__global__ __launch_bounds__(256) void roi_pool_kernel(
        const float* __restrict__ feat,   // (FH, FW, FC)
        const float* __restrict__ rois,   // (NROI, 4): x1,y1,x2,y2
        float* __restrict__ out)          // (NROI, PP, PP, FC)
{
    const int lane = threadIdx.x & 63;         // 4 channels per lane (float4)
    // wave-uniform output cell index, forced into an SGPR
    const int cell =
        __builtin_amdgcn_readfirstlane(blockIdx.x * 4 + (threadIdx.x >> 6));

    const int j = cell % PP;
    const int t = cell / PP;
    const int i = t % PP;
    const int r = t / PP;

    const float x1 = rois[r * 4 + 0];
    const float y1 = rois[r * 4 + 1];
    const float x2 = rois[r * 4 + 2];
    const float y2 = rois[r * 4 + 3];

    int xlo = (int)floorf(x1 * (float)FH);
    int xspan = (int)ceilf(x2 * (float)FH) - xlo;
    xspan = xspan > 1 ? xspan : 1;
    int ylo = (int)floorf(y1 * (float)FW);
    int yspan = (int)ceilf(y2 * (float)FW) - ylo;
    yspan = yspan > 1 ? yspan : 1;

    int xs, xlen, ys, ylen;
    bin_bounds(xlo, xspan, i, FH, xs, xlen);   // along H (axis 0)
    bin_bounds(ylo, yspan, j, FW, ys, ylen);   // along W (axis 1)

    const f32x4* __restrict__ f4 = (const f32x4*)feat;   // (FH, FW, FC/4)

    const int n = xlen * ylen;     // wave-uniform window size
    int sx = 0, sy = 0, idx = 0;   // wave-uniform walk counters

    f32x4 acc = { -INFINITY, -INFINITY, -INFINITY, -INFINITY };
    f32x4 va0, va1, va2, va3, vb0, vb1, vb2, vb3;

    // Compute next pixel offset; advance the walk only while valid pixels
    // remain (past n we keep re-reading the last pixel: no-op under max).
#define NEXT_OFF(off_) {                                          \
        int x_ = xs + sx; x_ = x_ > (FH - 1) ? (FH - 1) : x_;     \
        int y_ = ys + sy; y_ = y_ > (FW - 1) ? (FW - 1) : y_;     \
        off_ = (x_ * FW + y_) * (FC / 4) + lane;                  \
        if (idx + 1 < n) {                                        \
            int s_ = sy + 1;                                      \
            if (s_ == ylen) { sy = 0; ++sx; } else sy = s_;       \
        }                                                         \
        ++idx; }

#define LOAD4(a0_, a1_, a2_, a3_) {                               \
        int o0_, o1_, o2_, o3_;                                   \
        NEXT_OFF(o0_); NEXT_OFF(o1_); NEXT_OFF(o2_); NEXT_OFF(o3_);\
        a0_ = f4[o0_]; a1_ = f4[o1_]; a2_ = f4[o2_]; a3_ = f4[o3_]; }

#define FMAX1(a_) {                                               \
        acc.x = fmaxf(acc.x, a_.x);                               \
        acc.y = fmaxf(acc.y, a_.y);                               \
        acc.z = fmaxf(acc.z, a_.z);                               \
        acc.w = fmaxf(acc.w, a_.w); }

#define FMAX4(a0_, a1_, a2_, a3_) { FMAX1(a0_); FMAX1(a1_); FMAX1(a2_); FMAX1(a3_); }

    // prologue: chunk 0 in flight
    LOAD4(va0, va1, va2, va3);
    int done = CH;

    while (done < n) {
        LOAD4(vb0, vb1, vb2, vb3);        // issue chunk k+1
        FMAX4(va0, va1, va2, va3);        // consume chunk k  (vmcnt(4) wait)
        done += CH;
        if (done >= n) { FMAX4(vb0, vb1, vb2, vb3); goto fin; }
        LOAD4(va0, va1, va2, va3);
        FMAX4(vb0, vb1, vb2, vb3);
        done += CH;
    }
    FMAX4(va0, va1, va2, va3);            // n <= CH, or even-chunk exit
fin:

    {
        f32x4* dst = (f32x4*)out + (size_t)cell * (FC / 4) + lane;
        __builtin_nontemporal_store(acc, dst);   // don't pollute L2
    }

#undef NEXT_OFF
#undef LOAD4
#undef FMAX1
#undef FMAX4
}

extern "C" void kernel_launch(void* const* d_in, const int* in_sizes, int n_in,
                              void* d_out, int out_size, void* d_ws, size_t ws_size,
                              hipStream_t stream) {
    const float* feat = (const float*)d_in[0];   // (1,64,64,256)
    const float* rois = (const float*)d_in[1];   // (1,256,4)
    float* out = (float*)d_out;                  // (1,256,7,7,256)

    const int total_threads = NROI * PP * PP * 64;  // one wave per cell
    const int block = 256;
    const int grid = (total_threads + block - 1) / block;  // 3136
    roi_pool_kernel<<<grid, block, 0, stream>>>(feat, rois, out);
}